// Round 15
// baseline (97.781 us; speedup 1.0000x reference)
//
#include <hip/hip_runtime.h>

#define BB 16
#define CC 128
#define TT 128
#define HH 128
#define BC (BB*CC)   // 2048

typedef __attribute__((ext_vector_type(8))) short bf16x8;
typedef __attribute__((ext_vector_type(4))) float f32x4;

__device__ __forceinline__ unsigned short f2bf(float f) {
  union { float f; unsigned u; } v; v.f = f;
  unsigned u = v.u;
  u += 0x7FFFu + ((u >> 16) & 1u);   // round-to-nearest-even
  return (unsigned short)(u >> 16);
}

__device__ __forceinline__ bf16x8 pack8(f32x4 a, f32x4 b) {
  bf16x8 r;
  r[0] = (short)f2bf(a[0]); r[1] = (short)f2bf(a[1]);
  r[2] = (short)f2bf(a[2]); r[3] = (short)f2bf(a[3]);
  r[4] = (short)f2bf(b[0]); r[5] = (short)f2bf(b[1]);
  r[6] = (short)f2bf(b[2]); r[7] = (short)f2bf(b[3]);
  return r;
}

__device__ __forceinline__ float bf2f(unsigned short u) {
  union { unsigned u; float f; } v; v.u = ((unsigned)u) << 16; return v.f;
}

// async global->LDS, 16B per lane; LDS dest is wave-uniform base + lane*16
__device__ __forceinline__ void gl2lds16(const float* g, uint4* l) {
  __builtin_amdgcn_global_load_lds(
      (const __attribute__((address_space(1))) void*)g,
      (__attribute__((address_space(3))) void*)l, 16, 0, 0);
}

// ---- prep ------------------------------------------------------------------
// blk 0..47 : weight fragments (16x16x32 layout) + WaggT
// blk 48..303 : cpt/cp1 bias rows + cj2T (bf16, TRANSPOSED [col][row] pad 130)
// blk 304     : mask compaction
__global__ __launch_bounds__(256) void prep_kernel(
    const float* __restrict__ Wt, const float* __restrict__ Wc, const float* __restrict__ Wa,
    const float* __restrict__ clone, const float* __restrict__ food,
    const float* __restrict__ bt, const float* __restrict__ bcl,
    const int* __restrict__ tmask, const int* __restrict__ cmask,
    unsigned short* __restrict__ W2sw, unsigned short* __restrict__ Wcsw,
    unsigned short* __restrict__ WaggT,
    float* __restrict__ cpt, float* __restrict__ cp1,
    unsigned short* __restrict__ cj2T,
    unsigned short* __restrict__ agg,
    int* __restrict__ tidx, int* __restrict__ tcnt,
    int* __restrict__ cidx, int* __restrict__ ccnt) {
  const int blk = blockIdx.x, tid = threadIdx.x;
  if (blk < 48) {
    int i = blk * 256 + tid;
    if (i < 2048) {                       // thorn frags: 32 frags x 64 lanes
      int f = i >> 6, l = i & 63;
      int kt = f >> 3, n = f & 7;
      int ncol = n * 16 + (l & 15);
      int k0 = kt * 32 + (l >> 4) * 8;
      unsigned short o[8];
      #pragma unroll
      for (int e = 0; e < 8; ++e) o[e] = f2bf(Wt[(128 + k0 + e) * 128 + ncol]);
      *(uint4*)&W2sw[i * 8] = *(uint4*)o;
    } else if (i < 4096) {                // clone W3 frags: 32 frags x 64 lanes
      int j = i - 2048;
      int f = j >> 6, l = j & 63;
      int kt = f >> 3, n = f & 7;
      int ncol = n * 16 + (l & 15);
      int k0 = kt * 32 + (l >> 4) * 8;
      unsigned short o[8];
      #pragma unroll
      for (int e = 0; e < 8; ++e) o[e] = f2bf(Wc[(256 + k0 + e) * 128 + ncol]);
      *(uint4*)&Wcsw[j * 8] = *(uint4*)o;
    } else {                              // agg weights, plain [n][k] transpose
      int j = i - 4096;                   // [0, 8192)
      int n = j >> 6, k0 = (j & 63) * 8;
      unsigned short o[8];
      #pragma unroll
      for (int e = 0; e < 8; ++e) o[e] = f2bf(Wa[(k0 + e) * 128 + n]);
      *(uint4*)&WaggT[n * 512 + k0] = *(uint4*)o;
    }
  } else if (blk < 304) {
    // bias rows: 8 bc rows per block; 3 GEMVs per element
    const int bc0 = (blk - 48) * 8;
    __shared__ float cl[8][128];
    for (int i = tid; i < 1024; i += 256) cl[i >> 7][i & 127] = clone[bc0 * 128 + i];
    __syncthreads();
    const int k = tid & 127, r0 = (tid >> 7) * 4;
    float s1[4], s2[4], s3[4];
    #pragma unroll
    for (int r = 0; r < 4; ++r) { s1[r] = bt[k]; s2[r] = bcl[k]; s3[r] = 0.f; }
    #pragma unroll 4
    for (int h = 0; h < 128; ++h) {
      float w1 = Wt[h * 128 + k], w2 = Wc[h * 128 + k], w3 = Wc[(128 + h) * 128 + k];
      #pragma unroll
      for (int r = 0; r < 4; ++r) {
        float c = cl[r0 + r][h];
        s1[r] = fmaf(c, w1, s1[r]);
        s2[r] = fmaf(c, w2, s2[r]);
        s3[r] = fmaf(c, w3, s3[r]);
      }
    }
    unsigned short* ct = cj2T + (size_t)(bc0 >> 7) * 16640;   // [col][row] pad130
    const int bl = (bc0 & 127) + r0;
    #pragma unroll
    for (int r = 0; r < 4; ++r) {
      cpt[(bc0 + r0 + r) * 128 + k] = s1[r];
      cp1[(bc0 + r0 + r) * 128 + k] = s2[r];
      ct[k * 130 + bl + r] = f2bf(s3[r]);
    }
    for (int i = tid; i < 1024; i += 256) {
      int r = i >> 7, kk = i & 127;
      agg[(size_t)(bc0 + r) * 512 + kk]       = f2bf(cl[r][kk]);
      agg[(size_t)(bc0 + r) * 512 + 128 + kk] = f2bf(food[bc0 * 128 + i]);
    }
  } else {
    // mask compaction: thread i<32: b=i>>1, which=i&1; serial scan of 128 entries
    if (tid < 32) {
      int b = tid >> 1, which = tid & 1;
      const int* m = which ? cmask : tmask;
      int* idx = which ? cidx : tidx;
      int c = 0;
      for (int i = 0; i < 128; ++i)
        if (m[b * 128 + i]) idx[b * 128 + c++] = i;
      if (which) ccnt[b] = c; else tcnt[b] = c;
    }
  }
}

// ---- fused branch kernel: blocks 0..511 clone, 512..1023 thorn -------------
// 4 waves, wave-owns-tile (4 tiles/block), barrier-free loop. A-tile staged
// via global_load_lds into a per-wave PRIVATE double buffer (2x8KB), with
// manual counted s_waitcnt vmcnt(8) (never 0 mid-loop) so 8-16KB/wave stays
// in flight regardless of how the compiler schedules registers.
__global__ __launch_bounds__(256, 1) void branch15(
    const float* __restrict__ trel, const float* __restrict__ crel,
    const float* __restrict__ cpt, const float* __restrict__ cp1,
    const unsigned short* __restrict__ cj2T,
    const int* __restrict__ tidx, const int* __restrict__ tcnt,
    const int* __restrict__ cidx, const int* __restrict__ ccnt,
    const uint4* __restrict__ W2sw, const uint4* __restrict__ Wcsw,
    unsigned short* __restrict__ agg) {
  __shared__ uint4 Wlds[2048];                 // 32 KB
  __shared__ unsigned short cj2l[128 * 130];   // 32.5 KB (clone only)
  __shared__ int idxl[128];
  __shared__ uint4 Abuf[4096];                 // 64 KB: wave(4) x buf(2) x 512

  const bool isClone = blockIdx.x < 512;
  const int tileIdx = blockIdx.x & 511;
  const float* __restrict__ rel     = isClone ? crel  : trel;
  const float* __restrict__ biasrow = isClone ? cp1   : cpt;
  const int*   __restrict__ idxg    = isClone ? cidx  : tidx;
  const uint4* __restrict__ Wsw     = isClone ? Wcsw  : W2sw;
  const int aggoff = isClone ? 384 : 256;

  const int tid = threadIdx.x;
  const int wave = tid >> 6, lane = tid & 63;
  const int l16 = lane & 15, lk = lane >> 4;
  const int bc0 = tileIdx << 2;               // 4 tiles per block
  const int b = bc0 >> 7;
  const int cnt = (isClone ? ccnt : tcnt)[b];
  const int cl  = cnt > 0 ? cnt : 1;
  const int nact = (cnt + 15) >> 4;           // active row-groups (uniform)

  const int bc = bc0 + wave;                  // this wave's tile
  const float* Rb = rel + (size_t)bc * 16384;
  const int ABASE = wave * 1024;              // uint4 index of wave's A region

  // prologue: issue rg0's 8 async loads (row index straight from global idxg)
  if (nact > 0) {
    int rs0 = l16 < cl ? l16 : cl - 1;
    const float* rowp = Rb + (size_t)idxg[b * 128 + rs0] * 128 + lk * 8;
    #pragma unroll
    for (int q = 0; q < 8; ++q)
      gl2lds16(rowp + (q >> 1) * 32 + (q & 1) * 4, &Abuf[ABASE + q * 64]);
  }

  // stage W, idx, cj2T (plain 16B copies; cj2T pre-transposed+padded by prep)
  for (int i = tid; i < 2048; i += 256) Wlds[i] = Wsw[i];
  if (tid < 128) idxl[tid] = idxg[b * 128 + tid];
  if (isClone) {
    const uint4* cg = (const uint4*)(cj2T + (size_t)b * 16640);
    uint4* cd = (uint4*)cj2l;
    for (int i = tid; i < 2080; i += 256) cd[i] = cg[i];
  }
  __syncthreads();                            // ONLY barrier (drains vmcnt too)

  float bias[8];
  #pragma unroll
  for (int n = 0; n < 8; ++n) bias[n] = biasrow[bc * 128 + n * 16 + l16];

  float vmax[8];
  #pragma unroll
  for (int n = 0; n < 8; ++n) vmax[n] = 0.f;

  #pragma unroll 1
  for (int i = 0; i < nact; ++i) {
    const int cur = i & 1;
    const bool more = (i + 1 < nact);

    // issue NEXT rg's loads into the other buffer, then counted wait:
    // vmcnt(8) lets the 8 just-issued loads stay in flight while
    // guaranteeing the current buffer's loads have landed.
    if (more) {
      int rs = ((i + 1) << 4) + l16; if (rs >= cl) rs = cl - 1;
      const float* rowp = Rb + (size_t)idxl[rs] * 128 + lk * 8;
      const int nb = ABASE + ((i + 1) & 1) * 512;
      #pragma unroll
      for (int q = 0; q < 8; ++q)
        gl2lds16(rowp + (q >> 1) * 32 + (q & 1) * 4, &Abuf[nb + q * 64]);
      asm volatile("s_waitcnt vmcnt(8)" ::: "memory");
    } else {
      asm volatile("s_waitcnt vmcnt(0)" ::: "memory");
    }
    __builtin_amdgcn_sched_barrier(0);

    // read back this lane's 8x16B, convert to bf16 fragments
    const int rb = ABASE + cur * 512 + lane;
    bf16x8 afr[4];
    #pragma unroll
    for (int kt = 0; kt < 4; ++kt) {
      f32x4 a0 = *(const f32x4*)&Abuf[rb + (2 * kt) * 64];
      f32x4 a1 = *(const f32x4*)&Abuf[rb + (2 * kt + 1) * 64];
      afr[kt] = pack8(a0, a1);
    }

    f32x4 acc[8];
    #pragma unroll
    for (int n = 0; n < 8; ++n) acc[n] = (f32x4){0.f, 0.f, 0.f, 0.f};
    #pragma unroll
    for (int kt = 0; kt < 4; ++kt) {
      #pragma unroll
      for (int n = 0; n < 8; ++n) {
        bf16x8 bfr = *(const bf16x8*)&Wlds[(kt * 8 + n) * 64 + lane];
        acc[n] = __builtin_amdgcn_mfma_f32_16x16x32_bf16(afr[kt], bfr, acc[n], 0, 0, 0);
      }
    }

    if (isClone) {
      int rowj[4];                            // C/D row = lk*4+j (m89 layout)
      #pragma unroll
      for (int j = 0; j < 4; ++j) {
        int rj = (i << 4) + lk * 4 + j; if (rj >= cl) rj = cl - 1;
        rowj[j] = idxl[rj];
      }
      #pragma unroll
      for (int n = 0; n < 8; ++n) {
        const int col = n * 16 + l16;
        #pragma unroll
        for (int j = 0; j < 4; ++j) {
          float x = acc[n][j] + bias[n] + bf2f(cj2l[col * 130 + rowj[j]]);
          vmax[n] = fmaxf(vmax[n], fmaxf(x, 0.f));
        }
      }
    } else {
      #pragma unroll
      for (int n = 0; n < 8; ++n) {
        #pragma unroll
        for (int j = 0; j < 4; ++j)
          vmax[n] = fmaxf(vmax[n], fmaxf(acc[n][j] + bias[n], 0.f));
      }
    }
  }

  // per-wave reduction, direct store (no block barrier)
  unsigned short* aggw = agg + (size_t)bc * 512 + aggoff;
  #pragma unroll
  for (int n = 0; n < 8; ++n) {
    float v = vmax[n];
    v = fmaxf(v, __shfl_xor(v, 16));
    v = fmaxf(v, __shfl_xor(v, 32));
    if (lane < 16) aggw[n * 16 + lane] = f2bf(v);
  }
}

// ---- final: out = clone + relu(agg(2048x512) @ W_agg + b_agg) --------------
__global__ __launch_bounds__(256) void final_kernel(
    const unsigned short* __restrict__ agg, const unsigned short* __restrict__ WaggT,
    const float* __restrict__ clone, const float* __restrict__ bagg,
    float* __restrict__ out) {
  const int tid = threadIdx.x;
  const int wave = tid >> 6, lane = tid & 63;
  const int l16 = lane & 15, lk = lane >> 4;
  const int mrow = blockIdx.x * 16;

  f32x4 acc[2];
  acc[0] = (f32x4){0.f, 0.f, 0.f, 0.f};
  acc[1] = (f32x4){0.f, 0.f, 0.f, 0.f};
  #pragma unroll
  for (int kt = 0; kt < 16; ++kt) {
    bf16x8 a = *(const bf16x8*)(agg + (size_t)(mrow + l16) * 512 + kt * 32 + lk * 8);
    #pragma unroll
    for (int nn = 0; nn < 2; ++nn) {
      int ncol = (wave * 2 + nn) * 16 + l16;
      bf16x8 bfr = *(const bf16x8*)(WaggT + (size_t)ncol * 512 + kt * 32 + lk * 8);
      acc[nn] = __builtin_amdgcn_mfma_f32_16x16x32_bf16(a, bfr, acc[nn], 0, 0, 0);
    }
  }
  #pragma unroll
  for (int nn = 0; nn < 2; ++nn) {
    int col = (wave * 2 + nn) * 16 + l16;
    float bias = bagg[col];
    #pragma unroll
    for (int j = 0; j < 4; ++j) {
      int row = mrow + lk * 4 + j;
      out[row * 128 + col] = clone[row * 128 + col] + fmaxf(acc[nn][j] + bias, 0.f);
    }
  }
}

extern "C" void kernel_launch(void* const* d_in, const int* in_sizes, int n_in,
                              void* d_out, int out_size, void* d_ws, size_t ws_size,
                              hipStream_t stream) {
  const float* food  = (const float*)d_in[0];
  const float* trel  = (const float*)d_in[1];
  const float* clone = (const float*)d_in[2];
  const float* crel  = (const float*)d_in[3];
  const int*   tmask = (const int*)d_in[4];
  const int*   cmask = (const int*)d_in[5];
  const float* Wt    = (const float*)d_in[6];
  const float* bt    = (const float*)d_in[7];
  const float* Wc    = (const float*)d_in[8];
  const float* bcl   = (const float*)d_in[9];
  const float* Wa    = (const float*)d_in[10];
  const float* ba    = (const float*)d_in[11];
  float* out = (float*)d_out;

  char* w = (char*)d_ws;
  float* cpt = (float*)w;                      w += (size_t)BC * 128 * 4;
  float* cp1 = (float*)w;                      w += (size_t)BC * 128 * 4;
  unsigned short* cj2T  = (unsigned short*)w;  w += (size_t)16 * 16640 * 2;  // 520 KB
  unsigned short* W2sw  = (unsigned short*)w;  w += 32 * 64 * 8 * 2;     // 32 KB
  unsigned short* Wcsw  = (unsigned short*)w;  w += 32 * 64 * 8 * 2;     // 32 KB
  unsigned short* WaggT = (unsigned short*)w;  w += 128 * 512 * 2;       // 128 KB
  unsigned short* aggb  = (unsigned short*)w;  w += (size_t)BC * 512 * 2;
  int* tidx = (int*)w;                         w += 16 * 128 * 4;
  int* cidx = (int*)w;                         w += 16 * 128 * 4;
  int* tcnt = (int*)w;                         w += 16 * 4;
  int* ccnt = (int*)w;                         w += 16 * 4;

  prep_kernel<<<305, 256, 0, stream>>>(Wt, Wc, Wa, clone, food, bt, bcl,
                                       tmask, cmask,
                                       W2sw, Wcsw, WaggT, cpt, cp1, cj2T, aggb,
                                       tidx, tcnt, cidx, ccnt);
  branch15<<<1024, 256, 0, stream>>>(trel, crel, cpt, cp1, cj2T,
                                     tidx, tcnt, cidx, ccnt,
                                     (const uint4*)W2sw, (const uint4*)Wcsw, aggb);
  final_kernel<<<128, 256, 0, stream>>>(aggb, WaggT, clone, ba, out);
}

// Round 16
// 89.664 us; speedup vs baseline: 1.0905x; 1.0905x over previous
//
#include <hip/hip_runtime.h>

#define BB 16
#define CC 128
#define TT 128
#define HH 128
#define BC (BB*CC)   // 2048

typedef __attribute__((ext_vector_type(8))) short bf16x8;
typedef __attribute__((ext_vector_type(4))) float f32x4;

__device__ __forceinline__ unsigned short f2bf(float f) {
  union { float f; unsigned u; } v; v.f = f;
  unsigned u = v.u;
  u += 0x7FFFu + ((u >> 16) & 1u);   // round-to-nearest-even
  return (unsigned short)(u >> 16);
}

__device__ __forceinline__ bf16x8 pack8(f32x4 a, f32x4 b) {
  bf16x8 r;
  r[0] = (short)f2bf(a[0]); r[1] = (short)f2bf(a[1]);
  r[2] = (short)f2bf(a[2]); r[3] = (short)f2bf(a[3]);
  r[4] = (short)f2bf(b[0]); r[5] = (short)f2bf(b[1]);
  r[6] = (short)f2bf(b[2]); r[7] = (short)f2bf(b[3]);
  return r;
}

__device__ __forceinline__ float bf2f(unsigned short u) {
  union { unsigned u; float f; } v; v.u = ((unsigned)u) << 16; return v.f;
}

// ---- prep (unchanged from R15, validated incl. cj2T transpose) -------------
__global__ __launch_bounds__(256) void prep_kernel(
    const float* __restrict__ Wt, const float* __restrict__ Wc, const float* __restrict__ Wa,
    const float* __restrict__ clone, const float* __restrict__ food,
    const float* __restrict__ bt, const float* __restrict__ bcl,
    const int* __restrict__ tmask, const int* __restrict__ cmask,
    unsigned short* __restrict__ W2sw, unsigned short* __restrict__ Wcsw,
    unsigned short* __restrict__ WaggT,
    float* __restrict__ cpt, float* __restrict__ cp1,
    unsigned short* __restrict__ cj2T,
    unsigned short* __restrict__ agg,
    int* __restrict__ tidx, int* __restrict__ tcnt,
    int* __restrict__ cidx, int* __restrict__ ccnt) {
  const int blk = blockIdx.x, tid = threadIdx.x;
  if (blk < 48) {
    int i = blk * 256 + tid;
    if (i < 2048) {                       // thorn frags: 32 frags x 64 lanes
      int f = i >> 6, l = i & 63;
      int kt = f >> 3, n = f & 7;
      int ncol = n * 16 + (l & 15);
      int k0 = kt * 32 + (l >> 4) * 8;
      unsigned short o[8];
      #pragma unroll
      for (int e = 0; e < 8; ++e) o[e] = f2bf(Wt[(128 + k0 + e) * 128 + ncol]);
      *(uint4*)&W2sw[i * 8] = *(uint4*)o;
    } else if (i < 4096) {                // clone W3 frags: 32 frags x 64 lanes
      int j = i - 2048;
      int f = j >> 6, l = j & 63;
      int kt = f >> 3, n = f & 7;
      int ncol = n * 16 + (l & 15);
      int k0 = kt * 32 + (l >> 4) * 8;
      unsigned short o[8];
      #pragma unroll
      for (int e = 0; e < 8; ++e) o[e] = f2bf(Wc[(256 + k0 + e) * 128 + ncol]);
      *(uint4*)&Wcsw[j * 8] = *(uint4*)o;
    } else {                              // agg weights, plain [n][k] transpose
      int j = i - 4096;                   // [0, 8192)
      int n = j >> 6, k0 = (j & 63) * 8;
      unsigned short o[8];
      #pragma unroll
      for (int e = 0; e < 8; ++e) o[e] = f2bf(Wa[(k0 + e) * 128 + n]);
      *(uint4*)&WaggT[n * 512 + k0] = *(uint4*)o;
    }
  } else if (blk < 304) {
    // bias rows: 8 bc rows per block; 3 GEMVs per element
    const int bc0 = (blk - 48) * 8;
    __shared__ float cl[8][128];
    for (int i = tid; i < 1024; i += 256) cl[i >> 7][i & 127] = clone[bc0 * 128 + i];
    __syncthreads();
    const int k = tid & 127, r0 = (tid >> 7) * 4;
    float s1[4], s2[4], s3[4];
    #pragma unroll
    for (int r = 0; r < 4; ++r) { s1[r] = bt[k]; s2[r] = bcl[k]; s3[r] = 0.f; }
    #pragma unroll 4
    for (int h = 0; h < 128; ++h) {
      float w1 = Wt[h * 128 + k], w2 = Wc[h * 128 + k], w3 = Wc[(128 + h) * 128 + k];
      #pragma unroll
      for (int r = 0; r < 4; ++r) {
        float c = cl[r0 + r][h];
        s1[r] = fmaf(c, w1, s1[r]);
        s2[r] = fmaf(c, w2, s2[r]);
        s3[r] = fmaf(c, w3, s3[r]);
      }
    }
    unsigned short* ct = cj2T + (size_t)(bc0 >> 7) * 16640;   // [col][row] pad130
    const int bl = (bc0 & 127) + r0;
    #pragma unroll
    for (int r = 0; r < 4; ++r) {
      cpt[(bc0 + r0 + r) * 128 + k] = s1[r];
      cp1[(bc0 + r0 + r) * 128 + k] = s2[r];
      ct[k * 130 + bl + r] = f2bf(s3[r]);
    }
    for (int i = tid; i < 1024; i += 256) {
      int r = i >> 7, kk = i & 127;
      agg[(size_t)(bc0 + r) * 512 + kk]       = f2bf(cl[r][kk]);
      agg[(size_t)(bc0 + r) * 512 + 128 + kk] = f2bf(food[bc0 * 128 + i]);
    }
  } else {
    // mask compaction: thread i<32: b=i>>1, which=i&1; serial scan of 128 entries
    if (tid < 32) {
      int b = tid >> 1, which = tid & 1;
      const int* m = which ? cmask : tmask;
      int* idx = which ? cidx : tidx;
      int c = 0;
      for (int i = 0; i < 128; ++i)
        if (m[b * 128 + i]) idx[b * 128 + c++] = i;
      if (which) ccnt[b] = c; else tcnt[b] = c;
    }
  }
}

// ---- fused branch kernel: 2048 blocks ---------------------------------------
// blocks 0..1023 clone, 1024..2047 thorn; within branch: tb = i>>1, half = i&1
// (halves interleaved so the two half-blocks of a tile dispatch adjacently).
// 256 thr = 4 waves; wave w owns tile bc0+w for ONE col-half (4 n-frags).
// LDS = 16KB W-half + idx -> 8 blocks/CU; launch_bounds(256,8) -> VGPR<=64
// -> 32 waves/CU (the HW cap): latency hidden by TLP, loads demand-issued.
// cj2 j-term gathered directly from global cj2T (L2-resident). Barrier-free
// static rg loop with wave-uniform skip; per-wave shfl max + direct store.
__global__ __launch_bounds__(256, 8) void branch17(
    const float* __restrict__ trel, const float* __restrict__ crel,
    const float* __restrict__ cpt, const float* __restrict__ cp1,
    const unsigned short* __restrict__ cj2T,
    const int* __restrict__ tidx, const int* __restrict__ tcnt,
    const int* __restrict__ cidx, const int* __restrict__ ccnt,
    const uint4* __restrict__ W2sw, const uint4* __restrict__ Wcsw,
    unsigned short* __restrict__ agg) {
  __shared__ uint4 Wlds[1024];                 // 16 KB: this col-half's 16 frags
  __shared__ int idxl[128];

  const int bx = blockIdx.x;
  const bool isClone = bx < 1024;
  const int bi = bx & 1023;
  const int tb = bi >> 1, half = bi & 1;
  const float* __restrict__ rel     = isClone ? crel  : trel;
  const float* __restrict__ biasrow = isClone ? cp1   : cpt;
  const int*   __restrict__ idxg    = isClone ? cidx  : tidx;
  const uint4* __restrict__ Wsw     = isClone ? Wcsw  : W2sw;
  const int aggoff = isClone ? 384 : 256;

  const int tid = threadIdx.x;
  const int wave = tid >> 6, lane = tid & 63;
  const int l16 = lane & 15, lk = lane >> 4;
  const int bc0 = tb << 2;                    // 4 tiles per block
  const int b = bc0 >> 7;                     // same b for all 4 tiles
  const int cnt = (isClone ? ccnt : tcnt)[b];
  const int cl  = cnt > 0 ? cnt : 1;

  // stage this half's W fragments: global frag f = kt*8 + half*4 + nl
  for (int i = tid; i < 1024; i += 256) {
    int fl = i >> 6, l = i & 63;              // fl = kt*4 + nl
    int kt = fl >> 2, nl = fl & 3;
    Wlds[i] = Wsw[(kt * 8 + half * 4 + nl) * 64 + l];
  }
  if (tid < 128) idxl[tid] = idxg[b * 128 + tid];
  __syncthreads();                            // ONLY barrier

  const int bc = bc0 + wave;                  // this wave's tile
  const float* Rb = rel + (size_t)bc * 16384 + lk * 8;
  const unsigned short* cjb = cj2T + (size_t)b * 16640;   // [col*130 + row]

  float bias[4];
  #pragma unroll
  for (int n = 0; n < 4; ++n)
    bias[n] = biasrow[bc * 128 + half * 64 + n * 16 + l16];

  float vmax[4];
  #pragma unroll
  for (int n = 0; n < 4; ++n) vmax[n] = 0.f;

  #pragma unroll 1
  for (int rg = 0; rg < 8; ++rg) {
    if ((rg << 4) < cnt) {                    // wave-uniform guard
      int rs = (rg << 4) + l16; if (rs >= cl) rs = cl - 1;
      const float* Rt = Rb + idxl[rs] * 128;
      bf16x8 afr[4];
      #pragma unroll
      for (int kt = 0; kt < 4; ++kt)
        afr[kt] = pack8(*(const f32x4*)(Rt + kt * 32),
                        *(const f32x4*)(Rt + kt * 32 + 4));

      f32x4 acc[4];
      #pragma unroll
      for (int n = 0; n < 4; ++n) acc[n] = (f32x4){0.f, 0.f, 0.f, 0.f};
      #pragma unroll
      for (int kt = 0; kt < 4; ++kt) {
        #pragma unroll
        for (int n = 0; n < 4; ++n) {
          bf16x8 bfr = *(const bf16x8*)&Wlds[(kt * 4 + n) * 64 + lane];
          acc[n] = __builtin_amdgcn_mfma_f32_16x16x32_bf16(afr[kt], bfr, acc[n], 0, 0, 0);
        }
      }

      if (isClone) {
        int rowj[4];                          // C/D row = lk*4+j (m89 layout)
        #pragma unroll
        for (int j = 0; j < 4; ++j) {
          int rj = (rg << 4) + lk * 4 + j; if (rj >= cl) rj = cl - 1;
          rowj[j] = idxl[rj];
        }
        #pragma unroll
        for (int n = 0; n < 4; ++n) {
          const int col = half * 64 + n * 16 + l16;
          #pragma unroll
          for (int j = 0; j < 4; ++j) {
            float x = acc[n][j] + bias[n] + bf2f(cjb[col * 130 + rowj[j]]);
            vmax[n] = fmaxf(vmax[n], fmaxf(x, 0.f));
          }
        }
      } else {
        #pragma unroll
        for (int n = 0; n < 4; ++n) {
          #pragma unroll
          for (int j = 0; j < 4; ++j)
            vmax[n] = fmaxf(vmax[n], fmaxf(acc[n][j] + bias[n], 0.f));
        }
      }
    }
  }

  // per-wave reduction, direct store (no block barrier)
  unsigned short* aggw = agg + (size_t)bc * 512 + aggoff + half * 64;
  #pragma unroll
  for (int n = 0; n < 4; ++n) {
    float v = vmax[n];
    v = fmaxf(v, __shfl_xor(v, 16));
    v = fmaxf(v, __shfl_xor(v, 32));
    if (lane < 16) aggw[n * 16 + lane] = f2bf(v);
  }
}

// ---- final: out = clone + relu(agg(2048x512) @ W_agg + b_agg) --------------
__global__ __launch_bounds__(256) void final_kernel(
    const unsigned short* __restrict__ agg, const unsigned short* __restrict__ WaggT,
    const float* __restrict__ clone, const float* __restrict__ bagg,
    float* __restrict__ out) {
  const int tid = threadIdx.x;
  const int wave = tid >> 6, lane = tid & 63;
  const int l16 = lane & 15, lk = lane >> 4;
  const int mrow = blockIdx.x * 16;

  f32x4 acc[2];
  acc[0] = (f32x4){0.f, 0.f, 0.f, 0.f};
  acc[1] = (f32x4){0.f, 0.f, 0.f, 0.f};
  #pragma unroll
  for (int kt = 0; kt < 16; ++kt) {
    bf16x8 a = *(const bf16x8*)(agg + (size_t)(mrow + l16) * 512 + kt * 32 + lk * 8);
    #pragma unroll
    for (int nn = 0; nn < 2; ++nn) {
      int ncol = (wave * 2 + nn) * 16 + l16;
      bf16x8 bfr = *(const bf16x8*)(WaggT + (size_t)ncol * 512 + kt * 32 + lk * 8);
      acc[nn] = __builtin_amdgcn_mfma_f32_16x16x32_bf16(a, bfr, acc[nn], 0, 0, 0);
    }
  }
  #pragma unroll
  for (int nn = 0; nn < 2; ++nn) {
    int col = (wave * 2 + nn) * 16 + l16;
    float bias = bagg[col];
    #pragma unroll
    for (int j = 0; j < 4; ++j) {
      int row = mrow + lk * 4 + j;
      out[row * 128 + col] = clone[row * 128 + col] + fmaxf(acc[nn][j] + bias, 0.f);
    }
  }
}

extern "C" void kernel_launch(void* const* d_in, const int* in_sizes, int n_in,
                              void* d_out, int out_size, void* d_ws, size_t ws_size,
                              hipStream_t stream) {
  const float* food  = (const float*)d_in[0];
  const float* trel  = (const float*)d_in[1];
  const float* clone = (const float*)d_in[2];
  const float* crel  = (const float*)d_in[3];
  const int*   tmask = (const int*)d_in[4];
  const int*   cmask = (const int*)d_in[5];
  const float* Wt    = (const float*)d_in[6];
  const float* bt    = (const float*)d_in[7];
  const float* Wc    = (const float*)d_in[8];
  const float* bcl   = (const float*)d_in[9];
  const float* Wa    = (const float*)d_in[10];
  const float* ba    = (const float*)d_in[11];
  float* out = (float*)d_out;

  char* w = (char*)d_ws;
  float* cpt = (float*)w;                      w += (size_t)BC * 128 * 4;
  float* cp1 = (float*)w;                      w += (size_t)BC * 128 * 4;
  unsigned short* cj2T  = (unsigned short*)w;  w += (size_t)16 * 16640 * 2;  // 520 KB
  unsigned short* W2sw  = (unsigned short*)w;  w += 32 * 64 * 8 * 2;     // 32 KB
  unsigned short* Wcsw  = (unsigned short*)w;  w += 32 * 64 * 8 * 2;     // 32 KB
  unsigned short* WaggT = (unsigned short*)w;  w += 128 * 512 * 2;       // 128 KB
  unsigned short* aggb  = (unsigned short*)w;  w += (size_t)BC * 512 * 2;
  int* tidx = (int*)w;                         w += 16 * 128 * 4;
  int* cidx = (int*)w;                         w += 16 * 128 * 4;
  int* tcnt = (int*)w;                         w += 16 * 4;
  int* ccnt = (int*)w;                         w += 16 * 4;

  prep_kernel<<<305, 256, 0, stream>>>(Wt, Wc, Wa, clone, food, bt, bcl,
                                       tmask, cmask,
                                       W2sw, Wcsw, WaggT, cpt, cp1, cj2T, aggb,
                                       tidx, tcnt, cidx, ccnt);
  branch17<<<2048, 256, 0, stream>>>(trel, crel, cpt, cp1, cj2T,
                                     tidx, tcnt, cidx, ccnt,
                                     (const uint4*)W2sw, (const uint4*)Wcsw, aggb);
  final_kernel<<<128, 256, 0, stream>>>(aggb, WaggT, clone, ba, out);
}

// Round 17
// 70.360 us; speedup vs baseline: 1.3897x; 1.2744x over previous
//
#include <hip/hip_runtime.h>
#include <hip/hip_bf16.h>

#define BB 16
#define CC 128
#define TT 128
#define HH 128
#define BC (BB*CC)   // 2048

typedef __attribute__((ext_vector_type(8))) short bf16x8;
typedef __attribute__((ext_vector_type(4))) float f32x4;
typedef __attribute__((ext_vector_type(16))) float f32x16;

__device__ __forceinline__ unsigned short f2bf(float f) {
  union { float f; unsigned u; } v; v.f = f;
  unsigned u = v.u;
  u += 0x7FFFu + ((u >> 16) & 1u);   // round-to-nearest-even
  return (unsigned short)(u >> 16);
}

// hot-path pack: native casts -> compiler emits v_cvt_pk_bf16_f32 (m240)
__device__ __forceinline__ bf16x8 pack8hw(f32x4 a, f32x4 b) {
  union { __hip_bfloat16 h; short s; } c;
  bf16x8 r;
  #pragma unroll
  for (int e = 0; e < 4; ++e) { c.h = __float2bfloat16(a[e]); r[e] = c.s; }
  #pragma unroll
  for (int e = 0; e < 4; ++e) { c.h = __float2bfloat16(b[e]); r[4 + e] = c.s; }
  return r;
}

__device__ __forceinline__ float bf2f(unsigned short u) {
  union { unsigned u; float f; } v; v.u = ((unsigned)u) << 16; return v.f;
}

// ---- prep ------------------------------------------------------------------
// blk 0..47 : W frags in 32x32x16 layout (frag f=ks*4+nb, lane l, elem e:
//   ncol=nb*32+(l&31), k=ks*16+(l>>5)*8+e; validated R7/R8) + WaggT
// blk 48..303 : cpt/cp1 bias rows + cj2T (bf16 transposed [col][row], pad 130)
// blk 304     : mask compaction
__global__ __launch_bounds__(256) void prep_kernel(
    const float* __restrict__ Wt, const float* __restrict__ Wc, const float* __restrict__ Wa,
    const float* __restrict__ clone, const float* __restrict__ food,
    const float* __restrict__ bt, const float* __restrict__ bcl,
    const int* __restrict__ tmask, const int* __restrict__ cmask,
    unsigned short* __restrict__ W2sw, unsigned short* __restrict__ Wcsw,
    unsigned short* __restrict__ WaggT,
    float* __restrict__ cpt, float* __restrict__ cp1,
    unsigned short* __restrict__ cj2T,
    unsigned short* __restrict__ agg,
    int* __restrict__ tidx, int* __restrict__ tcnt,
    int* __restrict__ cidx, int* __restrict__ ccnt) {
  const int blk = blockIdx.x, tid = threadIdx.x;
  if (blk < 48) {
    int i = blk * 256 + tid;
    if (i < 2048) {                       // thorn frags (32x32 layout)
      int f = i >> 6, l = i & 63;
      int ks = f >> 2, nb = f & 3;
      int ncol = nb * 32 + (l & 31);
      int k0 = ks * 16 + (l >> 5) * 8;
      unsigned short o[8];
      #pragma unroll
      for (int e = 0; e < 8; ++e) o[e] = f2bf(Wt[(128 + k0 + e) * 128 + ncol]);
      *(uint4*)&W2sw[i * 8] = *(uint4*)o;
    } else if (i < 4096) {                // clone W3 frags (32x32 layout)
      int j = i - 2048;
      int f = j >> 6, l = j & 63;
      int ks = f >> 2, nb = f & 3;
      int ncol = nb * 32 + (l & 31);
      int k0 = ks * 16 + (l >> 5) * 8;
      unsigned short o[8];
      #pragma unroll
      for (int e = 0; e < 8; ++e) o[e] = f2bf(Wc[(256 + k0 + e) * 128 + ncol]);
      *(uint4*)&Wcsw[j * 8] = *(uint4*)o;
    } else {                              // agg weights, plain [n][k] transpose
      int j = i - 4096;                   // [0, 8192)
      int n = j >> 6, k0 = (j & 63) * 8;
      unsigned short o[8];
      #pragma unroll
      for (int e = 0; e < 8; ++e) o[e] = f2bf(Wa[(k0 + e) * 128 + n]);
      *(uint4*)&WaggT[n * 512 + k0] = *(uint4*)o;
    }
  } else if (blk < 304) {
    // bias rows: 8 bc rows per block; 3 GEMVs per element
    const int bc0 = (blk - 48) * 8;
    __shared__ float cl[8][128];
    for (int i = tid; i < 1024; i += 256) cl[i >> 7][i & 127] = clone[bc0 * 128 + i];
    __syncthreads();
    const int k = tid & 127, r0 = (tid >> 7) * 4;
    float s1[4], s2[4], s3[4];
    #pragma unroll
    for (int r = 0; r < 4; ++r) { s1[r] = bt[k]; s2[r] = bcl[k]; s3[r] = 0.f; }
    #pragma unroll 4
    for (int h = 0; h < 128; ++h) {
      float w1 = Wt[h * 128 + k], w2 = Wc[h * 128 + k], w3 = Wc[(128 + h) * 128 + k];
      #pragma unroll
      for (int r = 0; r < 4; ++r) {
        float c = cl[r0 + r][h];
        s1[r] = fmaf(c, w1, s1[r]);
        s2[r] = fmaf(c, w2, s2[r]);
        s3[r] = fmaf(c, w3, s3[r]);
      }
    }
    unsigned short* ct = cj2T + (size_t)(bc0 >> 7) * 16640;   // [col][row] pad130
    const int bl = (bc0 & 127) + r0;
    #pragma unroll
    for (int r = 0; r < 4; ++r) {
      cpt[(bc0 + r0 + r) * 128 + k] = s1[r];
      cp1[(bc0 + r0 + r) * 128 + k] = s2[r];
      ct[k * 130 + bl + r] = f2bf(s3[r]);
    }
    for (int i = tid; i < 1024; i += 256) {
      int r = i >> 7, kk = i & 127;
      agg[(size_t)(bc0 + r) * 512 + kk]       = f2bf(cl[r][kk]);
      agg[(size_t)(bc0 + r) * 512 + 128 + kk] = f2bf(food[bc0 * 128 + i]);
    }
  } else {
    // mask compaction: thread i<32: b=i>>1, which=i&1; serial scan of 128 entries
    if (tid < 32) {
      int b = tid >> 1, which = tid & 1;
      const int* m = which ? cmask : tmask;
      int* idx = which ? cidx : tidx;
      int c = 0;
      for (int i = 0; i < 128; ++i)
        if (m[b * 128 + i]) idx[b * 128 + c++] = i;
      if (which) ccnt[b] = c; else tcnt[b] = c;
    }
  }
}

// ---- fused branch kernel: blocks 0..255 clone, 256..511 thorn --------------
// branch13 skeleton (barrier-free wave-owns-tile, static rg loop, uniform
// skip, compaction gather, cj2l epilogue) upgraded to 32x32x16 MFMA: 32 rows
// per rg share each 1KB B-fragment read -> LDS traffic and MFMA issue halve.
// Hot-path bf16 pack via native casts (v_cvt_pk). Epilogue reg-outer so no
// rowj array (static indexing only).
__global__ __launch_bounds__(512, 4) void branch18(
    const float* __restrict__ trel, const float* __restrict__ crel,
    const float* __restrict__ cpt, const float* __restrict__ cp1,
    const unsigned short* __restrict__ cj2T,
    const int* __restrict__ tidx, const int* __restrict__ tcnt,
    const int* __restrict__ cidx, const int* __restrict__ ccnt,
    const uint4* __restrict__ W2sw, const uint4* __restrict__ Wcsw,
    unsigned short* __restrict__ agg) {
  __shared__ uint4 Wlds[2048];                 // 32 KB (32 frags)
  __shared__ unsigned short cj2l[128 * 130];   // 32.5 KB (clone only)
  __shared__ int idxl[128];

  const bool isClone = blockIdx.x < 256;
  const int tileIdx = blockIdx.x & 255;
  const float* __restrict__ rel     = isClone ? crel  : trel;
  const float* __restrict__ biasrow = isClone ? cp1   : cpt;
  const int*   __restrict__ idxg    = isClone ? cidx  : tidx;
  const uint4* __restrict__ Wsw     = isClone ? Wcsw  : W2sw;
  const int aggoff = isClone ? 384 : 256;

  const int tid = threadIdx.x;
  const int wave = tid >> 6, lane = tid & 63;
  const int l32 = lane & 31, lh = lane >> 5;
  const int bc0 = tileIdx << 3;               // 8 tiles per block
  const int b = bc0 >> 7;                     // same b for all 8 tiles
  const int cnt = (isClone ? ccnt : tcnt)[b];
  const int cl  = cnt > 0 ? cnt : 1;

  for (int i = tid; i < 2048; i += 512) Wlds[i] = Wsw[i];
  if (tid < 128) idxl[tid] = idxg[b * 128 + tid];
  if (isClone) {                              // stage cj2T[b] (pre-transposed)
    const uint4* cg = (const uint4*)(cj2T + (size_t)b * 16640);
    uint4* cd = (uint4*)cj2l;
    for (int i = tid; i < 2080; i += 512) cd[i] = cg[i];
  }
  __syncthreads();                            // ONLY barrier

  const int bc = bc0 + wave;                  // this wave's tile
  const float* Rb = rel + (size_t)bc * 16384;

  float bias[4];
  #pragma unroll
  for (int nb = 0; nb < 4; ++nb)
    bias[nb] = biasrow[bc * 128 + nb * 32 + l32];

  float vmax[4];
  #pragma unroll
  for (int nb = 0; nb < 4; ++nb) vmax[nb] = 0.f;

  #pragma unroll 1
  for (int rg = 0; rg < 4; ++rg) {
    if ((rg << 5) < cnt) {                    // wave-uniform guard
      // gathered A row for this lane (A layout: row=l&31, k=(l>>5)*8+e)
      int rs = (rg << 5) + l32; if (rs >= cl) rs = cl - 1;
      const float* rowp = Rb + (size_t)idxl[rs] * 128 + lh * 8;

      f32x16 acc[4];
      #pragma unroll
      for (int nb = 0; nb < 4; ++nb)
        #pragma unroll
        for (int r = 0; r < 16; ++r) acc[nb][r] = 0.f;

      #pragma unroll
      for (int ks = 0; ks < 8; ++ks) {
        f32x4 a0 = *(const f32x4*)(rowp + ks * 16);
        f32x4 a1 = *(const f32x4*)(rowp + ks * 16 + 4);
        bf16x8 afr = pack8hw(a0, a1);
        #pragma unroll
        for (int nb = 0; nb < 4; ++nb) {
          bf16x8 bfr = *(const bf16x8*)&Wlds[(ks * 4 + nb) * 64 + lane];
          acc[nb] = __builtin_amdgcn_mfma_f32_32x32x16_bf16(afr, bfr, acc[nb], 0, 0, 0);
        }
      }

      // epilogue: C/D layout col=l&31, row=(reg&3)+8*(reg>>2)+4*(l>>5) (m74)
      if (isClone) {
        #pragma unroll
        for (int reg = 0; reg < 16; ++reg) {
          int rloc = (rg << 5) + (reg & 3) + 8 * (reg >> 2) + 4 * lh;
          if (rloc >= cl) rloc = cl - 1;
          const int rj = idxl[rloc];
          #pragma unroll
          for (int nb = 0; nb < 4; ++nb) {
            float x = acc[nb][reg] + bias[nb]
                    + bf2f(cj2l[(nb * 32 + l32) * 130 + rj]);
            vmax[nb] = fmaxf(vmax[nb], x);   // relu folded: vmax init 0
          }
        }
      } else {
        #pragma unroll
        for (int reg = 0; reg < 16; ++reg) {
          #pragma unroll
          for (int nb = 0; nb < 4; ++nb)
            vmax[nb] = fmaxf(vmax[nb], acc[nb][reg] + bias[nb]);
        }
      }
    }
  }

  // reduce across the two row-half groups (lh), store cols (lane<32)
  unsigned short* aggw = agg + (size_t)bc * 512 + aggoff;
  #pragma unroll
  for (int nb = 0; nb < 4; ++nb) {
    float v = fmaxf(vmax[nb], __shfl_xor(vmax[nb], 32));
    if (lane < 32) aggw[nb * 32 + l32] = f2bf(v);
  }
}

// ---- final: out = clone + relu(agg(2048x512) @ W_agg + b_agg) --------------
__global__ __launch_bounds__(256) void final_kernel(
    const unsigned short* __restrict__ agg, const unsigned short* __restrict__ WaggT,
    const float* __restrict__ clone, const float* __restrict__ bagg,
    float* __restrict__ out) {
  const int tid = threadIdx.x;
  const int wave = tid >> 6, lane = tid & 63;
  const int l16 = lane & 15, lk = lane >> 4;
  const int mrow = blockIdx.x * 16;

  f32x4 acc[2];
  acc[0] = (f32x4){0.f, 0.f, 0.f, 0.f};
  acc[1] = (f32x4){0.f, 0.f, 0.f, 0.f};
  #pragma unroll
  for (int kt = 0; kt < 16; ++kt) {
    bf16x8 a = *(const bf16x8*)(agg + (size_t)(mrow + l16) * 512 + kt * 32 + lk * 8);
    #pragma unroll
    for (int nn = 0; nn < 2; ++nn) {
      int ncol = (wave * 2 + nn) * 16 + l16;
      bf16x8 bfr = *(const bf16x8*)(WaggT + (size_t)ncol * 512 + kt * 32 + lk * 8);
      acc[nn] = __builtin_amdgcn_mfma_f32_16x16x32_bf16(a, bfr, acc[nn], 0, 0, 0);
    }
  }
  #pragma unroll
  for (int nn = 0; nn < 2; ++nn) {
    int col = (wave * 2 + nn) * 16 + l16;
    float bias = bagg[col];
    #pragma unroll
    for (int j = 0; j < 4; ++j) {
      int row = mrow + lk * 4 + j;
      out[row * 128 + col] = clone[row * 128 + col] + fmaxf(acc[nn][j] + bias, 0.f);
    }
  }
}

extern "C" void kernel_launch(void* const* d_in, const int* in_sizes, int n_in,
                              void* d_out, int out_size, void* d_ws, size_t ws_size,
                              hipStream_t stream) {
  const float* food  = (const float*)d_in[0];
  const float* trel  = (const float*)d_in[1];
  const float* clone = (const float*)d_in[2];
  const float* crel  = (const float*)d_in[3];
  const int*   tmask = (const int*)d_in[4];
  const int*   cmask = (const int*)d_in[5];
  const float* Wt    = (const float*)d_in[6];
  const float* bt    = (const float*)d_in[7];
  const float* Wc    = (const float*)d_in[8];
  const float* bcl   = (const float*)d_in[9];
  const float* Wa    = (const float*)d_in[10];
  const float* ba    = (const float*)d_in[11];
  float* out = (float*)d_out;

  char* w = (char*)d_ws;
  float* cpt = (float*)w;                      w += (size_t)BC * 128 * 4;
  float* cp1 = (float*)w;                      w += (size_t)BC * 128 * 4;
  unsigned short* cj2T  = (unsigned short*)w;  w += (size_t)16 * 16640 * 2;  // 520 KB
  unsigned short* W2sw  = (unsigned short*)w;  w += 32 * 64 * 8 * 2;     // 32 KB
  unsigned short* Wcsw  = (unsigned short*)w;  w += 32 * 64 * 8 * 2;     // 32 KB
  unsigned short* WaggT = (unsigned short*)w;  w += 128 * 512 * 2;       // 128 KB
  unsigned short* aggb  = (unsigned short*)w;  w += (size_t)BC * 512 * 2;
  int* tidx = (int*)w;                         w += 16 * 128 * 4;
  int* cidx = (int*)w;                         w += 16 * 128 * 4;
  int* tcnt = (int*)w;                         w += 16 * 4;
  int* ccnt = (int*)w;                         w += 16 * 4;

  prep_kernel<<<305, 256, 0, stream>>>(Wt, Wc, Wa, clone, food, bt, bcl,
                                       tmask, cmask,
                                       W2sw, Wcsw, WaggT, cpt, cp1, cj2T, aggb,
                                       tidx, tcnt, cidx, ccnt);
  branch18<<<512, 512, 0, stream>>>(trel, crel, cpt, cp1, cj2T,
                                    tidx, tcnt, cidx, ccnt,
                                    (const uint4*)W2sw, (const uint4*)Wcsw, aggb);
  final_kernel<<<128, 256, 0, stream>>>(aggb, WaggT, clone, ba, out);
}